// Round 1
// baseline (24.051 us; speedup 1.0000x reference)
//
#include <hip/hip_runtime.h>

// Problem constants (N=15)
#define NPERSON 15
#define NVAR    120    // 15 persons + 105 pair z-nodes
#define NGRAPH  680    // 120 vars + 105 h-factors + 455 g-factors
#define BATCH   64

// pair index for a<b among N=15: pairs with first=a count (14-a)
__device__ __forceinline__ int pair_index(int a, int b) {
    return a * (29 - a) / 2 + (b - a - 1);
}

__device__ __forceinline__ void pair_invert(int f, int& u, int& v) {
    int a = 0;
    while (f >= 14 - a) { f -= 14 - a; a++; }
    u = a; v = a + 1 + f;
}

__device__ __forceinline__ void triple_invert(int t, int& a, int& b, int& c) {
    int x = 0;
    while (t >= (14 - x) * (13 - x) / 2) { t -= (14 - x) * (13 - x) / 2; x++; }
    a = x;
    int y = x + 1;
    while (t >= 14 - y) { t -= 14 - y; y++; }
    b = y; c = y + 1 + t;
}

// Kernel 1: P[b][r][c] for r<120, c<32.
//   c<16 : vf[b,r] @ W_edge[0:128, c]   + b_edge[c]   (S half, bias folded)
//   c>=16: vf[b,r] @ W_edge[128:256, c-16]            (T half)
// block = 256 threads = 8 rows x 32 cols; grid = 64 batches * 15 row-tiles
__global__ __launch_bounds__(256) void gemm_p(
    const float* __restrict__ vf,     // [64][120][128]
    const float* __restrict__ W,      // [256][16]
    const float* __restrict__ bias,   // [16]
    float* __restrict__ P)            // [64][120][32]
{
    int tid = threadIdx.x;
    int c  = tid & 31;
    int rl = tid >> 5;
    int b  = blockIdx.x / 15;
    int rt = blockIdx.x % 15;
    int r  = rt * 8 + rl;

    const float4* v4 = (const float4*)(vf + ((long)b * NVAR + r) * 128);
    // column base: c>=16 -> skip 128 rows of W (128*16 floats)
    const float* wc = W + ((c >> 4) << 11) + (c & 15);

    float acc = (c < 16) ? bias[c] : 0.0f;
#pragma unroll
    for (int k4 = 0; k4 < 32; k4++) {
        float4 a = v4[k4];
        int k = k4 * 4;
        acc = fmaf(a.x, wc[(k + 0) * 16], acc);
        acc = fmaf(a.y, wc[(k + 1) * 16], acc);
        acc = fmaf(a.z, wc[(k + 2) * 16], acc);
        acc = fmaf(a.w, wc[(k + 3) * 16], acc);
    }
    P[((long)b * NVAR + r) * 32 + c] = acc;
}

// Kernel 2: out[b][i][c] = (1/14) * sum_e relu(S_i + T_nbr(e))
// block = 256 threads = 16 rows x 16 cols; grid = 64*680/16 = 2720
__global__ __launch_bounds__(256) void fgnn_out(
    const float* __restrict__ P,   // [64][120][32]
    float* __restrict__ out)       // [64][680][16]
{
    const float inv3  = 1.0f / 3.0f;
    const float inv14 = 1.0f / 14.0f;

    int tid = threadIdx.x;
    int c  = tid & 15;
    int lr = tid >> 4;
    int gr = blockIdx.x * 16 + lr;      // < 64*680
    int b  = gr / NGRAPH;
    int i  = gr - b * NGRAPH;
    const float* Pb = P + (long)b * NVAR * 32;

    float res;
    if (i < NPERSON) {
        // person u: 14 neighbors = h-factors of each pair containing u
        int u = i;
        float s   = Pb[i * 32 + c];
        float acc = 0.0f;
#pragma unroll
        for (int v2 = 0; v2 < 15; v2++) {
            if (v2 == u) continue;
            int a = u < v2 ? u : v2;
            int d = u < v2 ? v2 : u;
            int z = 15 + pair_index(a, d);
            float T = (Pb[a * 32 + 16 + c] + Pb[d * 32 + 16 + c] + Pb[z * 32 + 16 + c]) * inv3;
            acc += fmaxf(s + T, 0.0f);
        }
        res = acc * inv14;
    } else if (i < NVAR) {
        // pair z-node (u,v): 1 h-factor + 13 g-factors (triangles containing the pair)
        int f = i - 15;
        int u, v; pair_invert(f, u, v);
        float s  = Pb[i * 32 + c];
        float Tz = Pb[i * 32 + 16 + c];
        float Th = (Pb[u * 32 + 16 + c] + Pb[v * 32 + 16 + c] + Tz) * inv3;
        float acc = fmaxf(s + Th, 0.0f);
#pragma unroll
        for (int w = 0; w < 15; w++) {
            if (w == u || w == v) continue;
            int a1 = u < w ? u : w, b1 = u < w ? w : u;
            int a2 = v < w ? v : w, b2 = v < w ? w : v;
            int zuw = 15 + pair_index(a1, b1);
            int zvw = 15 + pair_index(a2, b2);
            float Tg = (Tz + Pb[zuw * 32 + 16 + c] + Pb[zvw * 32 + 16 + c]) * inv3;
            acc += fmaxf(s + Tg, 0.0f);
        }
        res = acc * inv14;
    } else if (i < 225) {
        // h-factor (u,v,z): neighbor list [u, v, z x12]
        int f = i - 120;
        int u, v; pair_invert(f, u, v);
        int z = 15 + f;
        float S = (Pb[u * 32 + c] + Pb[v * 32 + c] + Pb[z * 32 + c]) * inv3;
        res = (fmaxf(S + Pb[u * 32 + 16 + c], 0.0f) +
               fmaxf(S + Pb[v * 32 + 16 + c], 0.0f) +
               12.0f * fmaxf(S + Pb[z * 32 + 16 + c], 0.0f)) * inv14;
    } else {
        // g-factor (z1,z2,z3): neighbor list [z1, z2, z3 x12]
        int t = i - 225;
        int a, b2, c3; triple_invert(t, a, b2, c3);
        int z1 = 15 + pair_index(a, b2);
        int z2 = 15 + pair_index(a, c3);
        int z3 = 15 + pair_index(b2, c3);
        float S = (Pb[z1 * 32 + c] + Pb[z2 * 32 + c] + Pb[z3 * 32 + c]) * inv3;
        res = (fmaxf(S + Pb[z1 * 32 + 16 + c], 0.0f) +
               fmaxf(S + Pb[z2 * 32 + 16 + c], 0.0f) +
               12.0f * fmaxf(S + Pb[z3 * 32 + 16 + c], 0.0f)) * inv14;
    }
    out[(long)gr * 16 + c] = res;
}

extern "C" void kernel_launch(void* const* d_in, const int* in_sizes, int n_in,
                              void* d_out, int out_size, void* d_ws, size_t ws_size,
                              hipStream_t stream) {
    const float* vf   = (const float*)d_in[0];  // [64,120,128]
    const float* W    = (const float*)d_in[1];  // [256,16]
    const float* bias = (const float*)d_in[2];  // [16]
    float* P = (float*)d_ws;                    // [64,120,32] = 983 KB scratch
    float* o = (float*)d_out;                   // [64,680,16]

    gemm_p<<<BATCH * 15, 256, 0, stream>>>(vf, W, bias, P);
    fgnn_out<<<(BATCH * NGRAPH) / 16, 256, 0, stream>>>(P, o);
}